// Round 10
// baseline (95.674 us; speedup 1.0000x reference)
//
#include <hip/hip_runtime.h>

#define BATCH 32
#define FPW 4   // frames per wave

typedef float f32x4 __attribute__((ext_vector_type(4)));
typedef int   i32x4 __attribute__((ext_vector_type(4)));

// ---------------------------------------------------------------------------
// R10: batched-read variant. Block = (64,4); each wave owns FPW=4 consecutive
// frames; grid = (T/16, B) = 2048 blocks.
//
// vs R9 (A/B, one variable): instead of pipelining loads between per-frame
// store bursts, load ALL 4 frames upfront (12 x f32x4 = 48 payload VGPRs,
// one 12 KB read burst per wave), then emit one uninterrupted ~42 KB store
// stream. 4x fewer read/write direction switches at the memory controller.
// __launch_bounds__(256,5) caps VGPR ~102 so the payload stays in registers.
// ---------------------------------------------------------------------------
__global__ __launch_bounds__(256, 5)
void lr_batch_kernel(const float* __restrict__ x,
                     const int* __restrict__ dur,
                     float* __restrict__ out,
                     int T, int D, int max_len) {
    const int b = blockIdx.y;
    const int bx = blockIdx.x;                       // 0..T/16-1
    const int tid = threadIdx.y * 64 + threadIdx.x;  // 0..255
    const int lane = tid & 63;
    const int w = tid >> 6;                          // wave id 0..3

    __shared__ int cs[1024];   // T = 1024
    __shared__ int part[4];

    // --- block-wide inclusive scan of the dur row (4 ints per thread) ---
    const i32x4 d = reinterpret_cast<const i32x4*>(dur + b * T)[tid];
    const int s0 = d.x;
    const int s1 = s0 + d.y;
    const int s2 = s1 + d.z;
    const int s3 = s2 + d.w;

    int v = s3;
    #pragma unroll
    for (int off = 1; off < 64; off <<= 1) {
        int u = __shfl_up(v, off, 64);
        if (lane >= off) v += u;
    }
    if (lane == 63) part[w] = v;
    __syncthreads();

    int add = 0;
    if (w > 0) add += part[0];
    if (w > 1) add += part[1];
    if (w > 2) add += part[2];

    const int base = add + v - s3;
    cs[tid * 4 + 0] = base + s0;
    cs[tid * 4 + 1] = base + s1;
    cs[tid * 4 + 2] = base + s2;
    cs[tid * 4 + 3] = base + s3;
    __syncthreads();

    const int total = cs[T - 1];
    const int d4 = D >> 2;                           // 192

    // --- this wave's 4 consecutive frames and their output extents ---
    const int fbase = (bx * 4 + w) * FPW;
    int st[FPW + 1];
    st[0] = (fbase == 0) ? 0 : cs[fbase - 1];
    #pragma unroll
    for (int k = 0; k < FPW; ++k) st[k + 1] = cs[fbase + k];

    const f32x4* __restrict__ xb =
        reinterpret_cast<const f32x4*>(x + (size_t)b * T * D);

    // --- phase 1: one read burst — all 4 frames into registers ---
    f32x4 pay[FPW][3];
    #pragma unroll
    for (int k = 0; k < FPW; ++k) {
        if (st[k + 1] > st[k]) {                     // dur > 0
            const f32x4* sp = xb + (size_t)(fbase + k) * d4;
            pay[k][0] = __builtin_nontemporal_load(&sp[lane]);
            pay[k][1] = __builtin_nontemporal_load(&sp[lane + 64]);
            pay[k][2] = __builtin_nontemporal_load(&sp[lane + 128]);
        }
    }

    // --- phase 2: one uninterrupted store stream over all rows ---
    #pragma unroll
    for (int k = 0; k < FPW; ++k) {
        f32x4* __restrict__ dst =
            reinterpret_cast<f32x4*>(out + ((size_t)b * max_len + st[k]) * D);
        for (int j = st[k]; j < st[k + 1]; ++j) {
            __builtin_nontemporal_store(pay[k][0], &dst[lane]);
            __builtin_nontemporal_store(pay[k][1], &dst[lane + 64]);
            __builtin_nontemporal_store(pay[k][2], &dst[lane + 128]);
            dst += d4;
        }
    }

    // --- tail zero-fill: 256 waves of this batch stripe rows past total ---
    const int q = bx * 4 + w;                        // 0..255 within batch
    const int nq = (T / (4 * FPW)) * 4;              // 256 waves per batch
    const f32x4 z = (f32x4)(0.f);
    for (int t = total + q; t < max_len; t += nq) {
        f32x4* __restrict__ zp =
            reinterpret_cast<f32x4*>(out + ((size_t)b * max_len + t) * D);
        __builtin_nontemporal_store(z, &zp[lane]);
        __builtin_nontemporal_store(z, &zp[lane + 64]);
        __builtin_nontemporal_store(z, &zp[lane + 128]);
    }
}

extern "C" void kernel_launch(void* const* d_in, const int* in_sizes, int n_in,
                              void* d_out, int out_size, void* d_ws, size_t ws_size,
                              hipStream_t stream) {
    const float* x = (const float*)d_in[0];
    const int* dur = (const int*)d_in[1];
    float* out = (float*)d_out;

    const int BT = in_sizes[1];          // B*T
    const int B = BATCH;
    const int T = BT / B;                // 1024
    const int D = in_sizes[0] / BT;      // 768
    const int max_len = out_size / (B * D);

    dim3 block(64, 4);
    dim3 grid(T / (4 * FPW), B);         // (64, 32) = 2048 blocks
    lr_batch_kernel<<<grid, block, 0, stream>>>(x, dur, out, T, D, max_len);
}

// Round 11
// 85.829 us; speedup vs baseline: 1.1147x; 1.1147x over previous
//
#include <hip/hip_runtime.h>

#define BATCH 32

typedef float f32x4 __attribute__((ext_vector_type(4)));

// ---------------------------------------------------------------------------
// Kernel 1: build the global output-row -> source-row table.
// srcg[b*max_len + j] = b*T + t for j in [cs[t-1], cs[t]);  -1 for padded tail.
// One block of T=1024 threads per batch. ~460 KB in d_ws. Removes ALL
// per-batch logic / division / scan from the hot kernel.
// ---------------------------------------------------------------------------
__global__ void build_src_kernel(const int* __restrict__ dur,
                                 int* __restrict__ srcg,
                                 int T, int max_len) {
    const int b = blockIdx.x;
    const int tid = threadIdx.x;          // 0..T-1
    const int lane = tid & 63;
    const int w = tid >> 6;               // 0..15

    __shared__ int part[16];
    __shared__ int totsh;

    const int d = dur[b * T + tid];
    int v = d;
    #pragma unroll
    for (int off = 1; off < 64; off <<= 1) {
        int u = __shfl_up(v, off, 64);
        if (lane >= off) v += u;
    }
    if (lane == 63) part[w] = v;
    __syncthreads();
    if (w == 0 && lane < 16) {
        int p = part[lane];
        #pragma unroll
        for (int off = 1; off < 16; off <<= 1) {
            int u = __shfl_up(p, off, 16);
            if (lane >= off) p += u;
        }
        part[lane] = p;
    }
    __syncthreads();

    const int end = v + (w > 0 ? part[w - 1] : 0);  // inclusive cumsum at tid
    const int start = end - d;
    if (tid == T - 1) totsh = end;

    int* __restrict__ srow = srcg + (size_t)b * max_len;
    const int sval = b * T + tid;
    for (int j = start; j < end; ++j) srow[j] = sval;  // disjoint ranges
    __syncthreads();

    const int total = totsh;
    for (int i = total + tid; i < max_len; i += blockDim.x) srow[i] = -1;
}

// ---------------------------------------------------------------------------
// Kernel 2: swept gather-copy. 2048 blocks x 256 thr = 8192 waves, grid-stride
// over output rows: wave q writes rows q, q+8192, ... -> at any instant the
// 8192 concurrent waves write 8192 CONSECUTIVE rows (one compact ~24 MB
// window sweeping the output linearly) instead of 8192 scattered private
// streams. Frame loads by neighboring waves hit the same L2 lines.
// Dependent src->frame chain is software-pipelined: src prefetched 2 steps
// ahead, frame 1 step ahead — nothing dependent sits in front of the stores
// (R7's mistake). Frame loads plain (L2 reuse ~3.5x); stores NT.
// ---------------------------------------------------------------------------
__global__ __launch_bounds__(256, 8)
void expand_sweep_kernel(const float* __restrict__ x,
                         const int* __restrict__ srcg,
                         float* __restrict__ out,
                         int D, long R) {
    const int lane = threadIdx.x & 63;
    const long q = (long)((blockIdx.x * blockDim.x + threadIdx.x) >> 6);
    const long NW = (long)((gridDim.x * blockDim.x) >> 6);

    long r = q;
    if (r >= R) return;

    int s_cur = srcg[r];                  // wave-uniform
    long rn = r + NW;
    int s_nxt = (rn < R) ? srcg[rn] : -1;

    f32x4 a0 = (f32x4)(0.f), a1 = a0, a2 = a0;
    if (s_cur >= 0) {
        const f32x4* sp = reinterpret_cast<const f32x4*>(x + (size_t)s_cur * D);
        a0 = sp[lane]; a1 = sp[lane + 64]; a2 = sp[lane + 128];
    }

    while (true) {
        // issue next frame load early (1-step lookahead)
        f32x4 n0 = (f32x4)(0.f), n1 = n0, n2 = n0;
        if (rn < R && s_nxt >= 0) {
            const f32x4* sp = reinterpret_cast<const f32x4*>(x + (size_t)s_nxt * D);
            n0 = sp[lane]; n1 = sp[lane + 64]; n2 = sp[lane + 128];
        }
        // prefetch src two steps ahead
        const long rnn = rn + NW;
        const int s_nn = (rnn < R) ? srcg[rnn] : -1;

        // store current row (uninterrupted, addresses register-computed)
        f32x4* dst = reinterpret_cast<f32x4*>(out + (size_t)r * D);
        __builtin_nontemporal_store(a0, &dst[lane]);
        __builtin_nontemporal_store(a1, &dst[lane + 64]);
        __builtin_nontemporal_store(a2, &dst[lane + 128]);

        if (rn >= R) break;
        r = rn; rn = rnn;
        s_cur = s_nxt; s_nxt = s_nn;
        a0 = n0; a1 = n1; a2 = n2;
    }
}

extern "C" void kernel_launch(void* const* d_in, const int* in_sizes, int n_in,
                              void* d_out, int out_size, void* d_ws, size_t ws_size,
                              hipStream_t stream) {
    const float* x = (const float*)d_in[0];
    const int* dur = (const int*)d_in[1];
    float* out = (float*)d_out;

    const int BT = in_sizes[1];          // B*T
    const int B = BATCH;
    const int T = BT / B;                // 1024
    const int D = in_sizes[0] / BT;      // 768
    const int max_len = out_size / (B * D);

    int* srcg = (int*)d_ws;              // B*max_len ints (~460 KB)

    build_src_kernel<<<B, T, 0, stream>>>(dur, srcg, T, max_len);

    const long R = (long)B * max_len;
    expand_sweep_kernel<<<2048, 256, 0, stream>>>(x, srcg, out, D, R);
}